// Round 8
// baseline (1144.810 us; speedup 1.0000x reference)
//
#include <hip/hip_runtime.h>
#include <cstdint>

// ---------------------------------------------------------------------------
// NVFP4 fake-quant GEMM: out = fq4(x) @ fq4(w)^T + bias
// fq4: per-16-group (along K) scale = e4m3_rt(amax/6), values on e2m1 grid.
// dq = q*scale is EXACT in bf16 -> quantize to bf16 in d_ws, bf16-MFMA GEMM.
//
// GEMM v6 ("16-wave dbuf"): 256x256 tile, BK=64, 1024 threads = 16 waves
// (4M x 4N), per-wave 64x64 output -> acc[4][4] f32x4 = 64 regs. One frag
// set (a[4]+b[4] bf16x8) = 64 regs -> FULL fragment double-buffer fits in
// 256 VGPR (v5.x spilled at 8-wave/128x64 where acc=128 forbade this).
// Each phase: MFMA consumes the set read LAST phase (starts instantly);
// the 8 ds_reads for the next set fly under the 16-MFMA window.
//   phase A: rd SB=(t,ks1)[buf b]; MFMA(SA); lgkm(0); BAR
//   phase B: stage t+2->buf b; vmcnt(4); BAR; rd SA'=(t+1,ks0)[b^1]; MFMA(SB)
// 2 barriers + 1 counted vmcnt + 1 no-op lgkm per tile.
// WAR: all reads of buf b dep-drained (MFMA dep or lgkm0) before BAR(A);
// stage follows BAR(A). vmcnt(4)+BAR makes every wave's t+1 chunks visible
// before any wave reads buf b^1.
// ---------------------------------------------------------------------------

typedef __attribute__((ext_vector_type(8))) __bf16 bf16x8;
typedef __attribute__((ext_vector_type(4))) float f32x4;

typedef __attribute__((address_space(1))) void gvoid;
typedef __attribute__((address_space(3))) void lvoid;

__device__ __forceinline__ float fp8_e4m3_rt(float x) {
    if (x < 0.015625f) {
        return __builtin_rintf(x * 512.0f) * (1.0f / 512.0f);
    }
    unsigned u = __float_as_uint(x);
    unsigned lsb = (u >> 20) & 1u;
    u = (u + 0x7FFFFu + lsb) & ~0xFFFFFu;
    return __uint_as_float(u);
}

// Divide-free e2m1 bucket of fl32(|v|/scale) (exactness proved; absmax=0).
__device__ __forceinline__ uint2 quant_quad(float4 v) {
    float ax = fabsf(v.x), ay = fabsf(v.y), az = fabsf(v.z), aw = fabsf(v.w);
    float a = fmaxf(fmaxf(ax, ay), fmaxf(az, aw));
    a = fmaxf(a, __shfl_xor(a, 1));
    a = fmaxf(a, __shfl_xor(a, 2));
    float scale = fp8_e4m3_rt(a / 6.0f);
    float sN = -scale;
    float n0 = sN * 0x1p-27f;
    float n1 = sN * 0x1p-25f;
    float n2 = sN * 0x1p-24f;
    float n4 = sN * 0x1p-23f;
    float n6 = sN * 0x1p-22f;
    float e[4] = {v.x, v.y, v.z, v.w};
    unsigned r[4];
    #pragma unroll
    for (int i = 0; i < 4; ++i) {
        float av = fabsf(e[i]);
        float q =
            fmaf(sN, 0.25f, av) < n0 ? 0.0f :
            fmaf(sN, 0.75f, av) < n1 ? 0.5f :
            fmaf(sN, 1.25f, av) < n2 ? 1.0f :
            fmaf(sN, 1.75f, av) < n2 ? 1.5f :
            fmaf(sN, 2.5f,  av) < n4 ? 2.0f :
            fmaf(sN, 3.5f,  av) < n4 ? 3.0f :
            fmaf(sN, 5.0f,  av) < n6 ? 4.0f : 6.0f;
        float dq = q * scale;
        r[i] = (__float_as_uint(dq) | (__float_as_uint(e[i]) & 0x80000000u)) >> 16;
    }
    uint2 o;
    o.x = r[0] | (r[1] << 16);
    o.y = r[2] | (r[3] << 16);
    return o;
}

__global__ __launch_bounds__(256)
void quant_fp4_fused(const float* __restrict__ x, const float* __restrict__ w,
                     uint16_t* __restrict__ out, int xquads, int totquads) {
    const int half = totquads >> 1;
    const int t0 = blockIdx.x * 256 + threadIdx.x;
    uint2* o2 = (uint2*)out;
    if (t0 < half) {
        const float4* s0 = (t0 < xquads) ? ((const float4*)x) + t0
                                         : ((const float4*)w) + (t0 - xquads);
        o2[t0] = quant_quad(*s0);
    }
    const int q1 = t0 + half;
    if (q1 < totquads) {
        const float4* s1 = (q1 < xquads) ? ((const float4*)x) + q1
                                         : ((const float4*)w) + (q1 - xquads);
        o2[q1] = quant_quad(*s1);
    }
}

// ---------------------------------------------------------------------------
// GEMM. LDS: lds[2][2][256*64] bf16 = 128 KiB; (row,k) at row*64+(k^((row&7)<<3)).
// Staging: chunk c = i*1024 + tid (i<2) -> linear LDS elems [c*8, c*8+8):
// row = c>>3 (0..255), k = ((c&7)^(row&7))*8 (inverse swizzle). 4 DMA/thread
// per tile (2 A chunks + 2 B chunks), each wave's dest = chunk*8192 + wave*512.
// Frags (16x16x32): A row = wm*64 + fi*16 + l15, B row = wn*64 + fj*16 + l15,
// k = (lane>>4)*8 + j, swizzled kx = (ks*32 + hi16) ^ ((lane&7)*8).
// vmcnt ledger (per-wave, 4 DMA/tile): enter phase B with 4 (t+1) out-
// standing; stage 4 (t+2) -> 8; vmcnt(4) retires t+1's 4. Tails: vmcnt(0).
// ---------------------------------------------------------------------------
#define BK 64
#define THREADS 1024

#define SB __builtin_amdgcn_sched_barrier(0)
#define VMW(S) do { asm volatile("s_waitcnt vmcnt(" S ")" ::: "memory"); SB; } while (0)
#define LGKM0 do { asm volatile("s_waitcnt lgkmcnt(0)" ::: "memory"); SB; } while (0)
#define PHB do { SB; asm volatile("" ::: "memory");                           \
    __builtin_amdgcn_s_barrier();                                             \
    asm volatile("" ::: "memory"); SB; } while (0)

// Read one k-step set (4 A frags + 4 B frags) from buffer B_ at kx offset KX.
#define LDSET(AS, BS, B_, KX) do { _Pragma("unroll")                          \
    for (int f_ = 0; f_ < 4; ++f_)                                            \
        AS[f_] = *(const bf16x8*)&lds[B_][0][aBase + f_ * 1024 + (KX)];       \
    _Pragma("unroll")                                                         \
    for (int f_ = 0; f_ < 4; ++f_)                                            \
        BS[f_] = *(const bf16x8*)&lds[B_][1][bBase + f_ * 1024 + (KX)];       \
    SB; } while (0)

#define MSET(AS, BS) do {                                                     \
    __builtin_amdgcn_s_setprio(1);                                            \
    _Pragma("unroll") for (int fi_ = 0; fi_ < 4; ++fi_)                       \
    _Pragma("unroll") for (int fj_ = 0; fj_ < 4; ++fj_)                       \
        acc[fi_][fj_] = __builtin_amdgcn_mfma_f32_16x16x32_bf16(              \
            AS[fi_], BS[fj_], acc[fi_][fj_], 0, 0, 0);                        \
    __builtin_amdgcn_s_setprio(0); } while (0)

#define STGA(B_, ch, ko) __builtin_amdgcn_global_load_lds(                    \
    (gvoid*)(pA + (size_t)off[ch] + kAdv + (ko)),                             \
    (lvoid*)&lds[B_][0][(ch) * 8192 + ldsU], 16, 0, 0)
#define STGB(B_, ch, ko) __builtin_amdgcn_global_load_lds(                    \
    (gvoid*)(pB + (size_t)off[ch] + kAdv + (ko)),                             \
    (lvoid*)&lds[B_][1][(ch) * 8192 + ldsU], 16, 0, 0)
#define STG_ALL(B_, ko) do { STGA(B_, 0, ko); STGA(B_, 1, ko);                \
    STGB(B_, 0, ko); STGB(B_, 1, ko); } while (0)

// One K-tile t (buffer B_). Enter with SA=(t,ks0) in a0v/b0v.
#define KTILE(B_, STG_, AHD_, SK_, WS) do {                                   \
    /* phase A: read SB=(t,ks1); MFMA(SA) runs over it */                     \
    LDSET(a1v, b1v, B_, kx1);                                                 \
    MSET(a0v, b0v);                                                           \
    LGKM0;                                                                    \
    PHB;                                                                      \
    /* phase B: stage t+2; t+1 visible; read SA'=(t+1,ks0); MFMA(SB) */       \
    if (STG_) { STG_ALL(B_, SK_); }                                           \
    VMW(WS);                                                                  \
    PHB;                                                                      \
    if (AHD_) { LDSET(a0v, b0v, (B_) ^ 1, kx0); }                             \
    MSET(a1v, b1v);                                                           \
} while (0)

__global__ __launch_bounds__(THREADS, 1)
void gemm_w4a4(const uint16_t* __restrict__ Aq, const uint16_t* __restrict__ Bq,
               const float* __restrict__ bias, float* __restrict__ C,
               int M, int N, int K) {
    __shared__ __align__(16) uint16_t lds[2][2][256 * BK];

    const int tid  = threadIdx.x;
    const int wave = tid >> 6;             // 0..15
    const int lane = tid & 63;
    const int wm   = wave >> 2;            // 0..3  (m quarter)
    const int wn   = wave & 3;             // 0..3  (n quarter)
    const int l15  = lane & 15;
    const int hi16 = (lane >> 4) << 3;     // 0/8/16/24 (frag k subgroup)
    const int rsw  = (lane & 7) << 3;      // row-swizzle XOR (elems)
    const int kx0  = hi16 ^ rsw;           // k-step 0
    const int kx1  = (32 + hi16) ^ rsw;    // k-step 1
    const int aBase = ((wm << 6) + l15) << 6;   // A frag row * 64
    const int bBase = ((wn << 6) + l15) << 6;   // B frag row * 64
    const int ldsU  = wave << 9;                // wave*512 elems (stage base)

    // ---- bijective XCD swizzle (T1, m204); column-major tile order ----
    const int ntm = M >> 8, nwg = ntm * (N >> 8);
    const int bid = blockIdx.x;
    const int q8 = nwg >> 3, r8 = nwg & 7;
    const int xcd = bid & 7;
    const int wgid = (xcd < r8 ? xcd * (q8 + 1) : r8 * (q8 + 1) + (xcd - r8) * q8)
                     + (bid >> 3);
    const int mBase = (wgid % ntm) << 8;
    const int nBase = (wgid / ntm) << 8;

    // ---- staging source offsets (inverse-swizzled, shared A/B) ----
    uint32_t off[2];
    #pragma unroll
    for (int i = 0; i < 2; ++i) {
        const int c = i * THREADS + tid;
        const int row = c >> 3;
        const int kc = ((c & 7) ^ (row & 7)) << 3;
        off[i] = (uint32_t)row * (uint32_t)K + (uint32_t)kc;
    }
    const uint16_t* pA = Aq + (size_t)mBase * K;
    const uint16_t* pB = Bq + (size_t)nBase * K;

    const int nt = K / BK;   // even, >= 4 (K=4096 -> 64)
    uint32_t kAdv = 0;

    // ---- prologue: stage t0 then t1 (4 DMA/thread each) ----
    STG_ALL(0, 0);
    STG_ALL(1, 64);
    VMW("4");                // own t0 chunks landed
    PHB;                     // all waves' t0 chunks visible

    f32x4 acc[4][4] = {};
    bf16x8 a0v[4], b0v[4], a1v[4], b1v[4];

    // SA = (t0, ks0)
    LDSET(a0v, b0v, 0, kx0);

    kAdv = 2 * BK;   // during pair starting at tk: tile tk+2's k (SK_=0 path)

    for (int tk = 0; tk < nt - 2; tk += 2) {
        KTILE(0, 1, 1, 0,  "4");
        KTILE(1, 1, 1, 64, "4");
        kAdv += 2 * BK;
    }
    // tails: tile nt-2 (no staging; t+1 = nt-1 must fully land -> vmcnt(0)),
    // then tile nt-1 (nothing outstanding, no ahead-read).
    KTILE(0, 0, 1, 0, "0");
    KTILE(1, 0, 0, 0, "0");

    // ---- epilogue: C/D col = lane&15, row = (lane>>4)*4 + reg ----
    const int rq = (lane >> 4) << 2;
    #pragma unroll
    for (int fj = 0; fj < 4; ++fj) {
        const int col = nBase + (wn << 6) + fj * 16 + l15;
        const float bj = bias[col];
        #pragma unroll
        for (int fi = 0; fi < 4; ++fi) {
            const int row0 = mBase + (wm << 6) + fi * 16 + rq;
            #pragma unroll
            for (int r = 0; r < 4; ++r)
                C[(size_t)(row0 + r) * N + col] = acc[fi][fj][r] + bj;
        }
    }
}

extern "C" void kernel_launch(void* const* d_in, const int* in_sizes, int n_in,
                              void* d_out, int out_size, void* d_ws, size_t ws_size,
                              hipStream_t stream) {
    const float* x    = (const float*)d_in[0];
    const float* w    = (const float*)d_in[1];
    const float* bias = (const float*)d_in[2];
    float* out = (float*)d_out;

    const int N = in_sizes[2];
    const int K = in_sizes[1] / N;
    const int M = in_sizes[0] / K;

    uint16_t* xq = (uint16_t*)d_ws;
    uint16_t* wq = xq + (size_t)M * K;

    const int xquads = (M * K) / 4;
    const int totquads = xquads + (N * K) / 4;
    const int half = totquads / 2;
    quant_fp4_fused<<<(half + 255) / 256, 256, 0, stream>>>(x, w, xq, xquads, totquads);

    const int nwg = (M >> 8) * (N >> 8);
    gemm_w4a4<<<nwg, THREADS, 0, stream>>>(xq, wq, bias, out, M, N, K);
}

// Round 9
// 500.722 us; speedup vs baseline: 2.2863x; 2.2863x over previous
//
#include <hip/hip_runtime.h>
#include <cstdint>

// ---------------------------------------------------------------------------
// NVFP4 fake-quant GEMM: out = fq4(x) @ fq4(w)^T + bias
// fq4: per-16-group (along K) scale = e4m3_rt(amax/6), values on e2m1 grid.
// dq = q*scale is EXACT in bf16 -> quantize into bf16 buffers in d_ws, then
// bf16-MFMA GEMM (round-1 structure, best measured: 272us, MfmaUtil 43.5).
//
// Round 9: GEMM is round-1 VERBATIM. Quant rewritten shfl-free: one thread
// per 16-elem group (amax = 15 local fmax, no cross-lane/DS ops), div-free
// e2m1 bucket (exactness proven, absmax=0 rounds 2-8), uint4 stores.
// ---------------------------------------------------------------------------

typedef __attribute__((ext_vector_type(8))) __bf16 bf16x8;
typedef __attribute__((ext_vector_type(4))) float f32x4;

typedef __attribute__((address_space(1))) void gvoid;
typedef __attribute__((address_space(3))) void lvoid;

__device__ __forceinline__ float fp8_e4m3_rt(float x) {
    if (x < 0.015625f) {
        return __builtin_rintf(x * 512.0f) * (1.0f / 512.0f);
    }
    unsigned u = __float_as_uint(x);
    unsigned lsb = (u >> 20) & 1u;
    u = (u + 0x7FFFFu + lsb) & ~0xFFFFFu;
    return __uint_as_float(u);
}

// Divide-free e2m1 bucket of fl32(|v|/scale): ref condition fl(|v|/s) < t
// <=> fmaf(-s, t, |v|) < -s*(halfulp below t); ties impossible (4-bit
// mantissa scale x odd 25-bit boundary never representable in fp32).
__device__ __forceinline__ unsigned q1e(float e, float scale, float sN,
                                        float n0, float n1, float n2,
                                        float n4, float n6) {
    float av = fabsf(e);
    float q =
        fmaf(sN, 0.25f, av) < n0 ? 0.0f :
        fmaf(sN, 0.75f, av) < n1 ? 0.5f :
        fmaf(sN, 1.25f, av) < n2 ? 1.0f :
        fmaf(sN, 1.75f, av) < n2 ? 1.5f :
        fmaf(sN, 2.5f,  av) < n4 ? 2.0f :
        fmaf(sN, 3.5f,  av) < n4 ? 3.0f :
        fmaf(sN, 5.0f,  av) < n6 ? 4.0f : 6.0f;
    float dq = q * scale;                    // exact, >= 0
    return (__float_as_uint(dq) | (__float_as_uint(e) & 0x80000000u)) >> 16;
}

// One thread = one 16-element group (64 B in, 32 B out). No cross-lane ops.
__global__ __launch_bounds__(256)
void quant_fp4_g16(const float* __restrict__ x, const float* __restrict__ w,
                   uint16_t* __restrict__ out, int xgroups, int totgroups) {
    const int g = blockIdx.x * 256 + threadIdx.x;
    if (g >= totgroups) return;
    const float4* s = (g < xgroups)
        ? (const float4*)x + (size_t)g * 4
        : (const float4*)w + (size_t)(g - xgroups) * 4;
    float4 v0 = s[0], v1 = s[1], v2 = s[2], v3 = s[3];

    float a0 = fmaxf(fmaxf(fabsf(v0.x), fabsf(v0.y)), fmaxf(fabsf(v0.z), fabsf(v0.w)));
    float a1 = fmaxf(fmaxf(fabsf(v1.x), fabsf(v1.y)), fmaxf(fabsf(v1.z), fabsf(v1.w)));
    float a2 = fmaxf(fmaxf(fabsf(v2.x), fabsf(v2.y)), fmaxf(fabsf(v2.z), fabsf(v2.w)));
    float a3 = fmaxf(fmaxf(fabsf(v3.x), fabsf(v3.y)), fmaxf(fabsf(v3.z), fabsf(v3.w)));
    float a = fmaxf(fmaxf(a0, a1), fmaxf(a2, a3));

    float scale = fp8_e4m3_rt(a / 6.0f);     // exact fp32 div, like ref
    float sN = -scale;
    float n0 = sN * 0x1p-27f;   // t=0.25
    float n1 = sN * 0x1p-25f;   // t=0.75
    float n2 = sN * 0x1p-24f;   // t=1.25, 1.75
    float n4 = sN * 0x1p-23f;   // t=2.5, 3.5
    float n6 = sN * 0x1p-22f;   // t=5

    #define Q1(e) q1e((e), scale, sN, n0, n1, n2, n4, n6)
    uint4 o0, o1;
    o0.x = Q1(v0.x) | (Q1(v0.y) << 16);
    o0.y = Q1(v0.z) | (Q1(v0.w) << 16);
    o0.z = Q1(v1.x) | (Q1(v1.y) << 16);
    o0.w = Q1(v1.z) | (Q1(v1.w) << 16);
    o1.x = Q1(v2.x) | (Q1(v2.y) << 16);
    o1.y = Q1(v2.z) | (Q1(v2.w) << 16);
    o1.z = Q1(v3.x) | (Q1(v3.y) << 16);
    o1.w = Q1(v3.z) | (Q1(v3.w) << 16);
    #undef Q1

    ((uint4*)out)[(size_t)g * 2]     = o0;
    ((uint4*)out)[(size_t)g * 2 + 1] = o1;
}

// ---------------------------------------------------------------------------
// bf16 GEMM, C[M,N] = A[M,K] * B[N,K]^T + bias. ROUND-1 VERBATIM.
// 256x256 tile, BK=64, 8 waves (2Mx4N), per-wave 128x64, 16x16x32 MFMA.
// LDS 128 KiB double-buffered, XOR-swizzled; 4-phase quadrant schedule,
// counted vmcnt(8), setprio around MFMA clusters, bijective XCD swizzle.
// ---------------------------------------------------------------------------
#define BM 256
#define BN 256
#define BK 64
#define THREADS 512

__device__ __forceinline__ void barfence() {
    asm volatile("" ::: "memory");
    __builtin_amdgcn_s_barrier();
    asm volatile("" ::: "memory");
}

#define STG_A(bb, i, kk)                                                     \
    __builtin_amdgcn_global_load_lds((gvoid*)(Aq + (size_t)offA[i] + (kk)),  \
        (lvoid*)&lds[bb][0][ldsU + (i) * 4096], 16, 0, 0)
#define STG_B(bb, i, kk)                                                     \
    __builtin_amdgcn_global_load_lds((gvoid*)(Bq + (size_t)offB[i] + (kk)),  \
        (lvoid*)&lds[bb][1][ldsU + (i) * 4096], 16, 0, 0)

#define MFMA16(AH, BH, MH, NH)                                               \
    _Pragma("unroll")                                                        \
    for (int fi = 0; fi < 4; ++fi) {                                         \
        _Pragma("unroll")                                                    \
        for (int fj = 0; fj < 2; ++fj) {                                     \
            f32x4 c = acc[(MH) * 4 + fi][(NH) * 2 + fj];                     \
            c = __builtin_amdgcn_mfma_f32_16x16x32_bf16(AH[fi][0], BH[fj][0], c, 0, 0, 0); \
            c = __builtin_amdgcn_mfma_f32_16x16x32_bf16(AH[fi][1], BH[fj][1], c, 0, 0, 0); \
            acc[(MH) * 4 + fi][(NH) * 2 + fj] = c;                           \
        }                                                                    \
    }

__global__ __launch_bounds__(THREADS, 2)
void gemm_w4a4(const uint16_t* __restrict__ Aq, const uint16_t* __restrict__ Bq,
               const float* __restrict__ bias, float* __restrict__ C,
               int M, int N, int K) {
    __shared__ __align__(16) uint16_t lds[2][2][BM * BK];

    const int tid  = threadIdx.x;
    const int wave = tid >> 6;
    const int lane = tid & 63;
    const int wm   = wave >> 2;            // 0..1
    const int wn   = wave & 3;             // 0..3
    const int l15  = lane & 15;
    const int l7   = lane & 7;
    const int hi8  = (lane >> 4) << 3;
    const int hi4  = (lane >> 4) << 2;
    const int kx0  = hi8 ^ (l7 << 3);           // swizzled k-offset, ks=0
    const int kx1  = (32 + hi8) ^ (l7 << 3);    // swizzled k-offset, ks=1
    const int aBase = ((wm << 7) + l15) << 6;   // row*64 within A region
    const int bBase = ((wn << 6) + l15) << 6;   // row*64 within B region
    const int ldsU  = wave << 9;                // wave-uniform stage base (elems)

    // ---- tile decomposition + bijective XCD swizzle (T1, m204) ----
    const int ntm = M >> 8, ntn = N >> 8, nwg = ntm * ntn;
    const int bid = blockIdx.x;
    const int q8 = nwg >> 3, r8 = nwg & 7;
    const int xcd = bid & 7;
    const int wgid = (xcd < r8 ? xcd * (q8 + 1) : r8 * (q8 + 1) + (xcd - r8) * q8)
                     + (bid >> 3);
    const int mBase = (wgid % ntm) << 8;   // column-major: XCD shares B panel
    const int nBase = (wgid / ntm) << 8;
    (void)ntn;

    // ---- staging source offsets (inverse-swizzled, loop-invariant) ----
    uint32_t offA[4], offB[4];
    #pragma unroll
    for (int i = 0; i < 4; ++i) {
        const int c   = i * THREADS + tid;
        const int row = c >> 3;
        const int kc  = ((c & 7) ^ (row & 7)) << 3;
        offA[i] = (uint32_t)(mBase + row) * (uint32_t)K + (uint32_t)kc;
        offB[i] = (uint32_t)(nBase + row) * (uint32_t)K + (uint32_t)kc;
    }

    const int nt = K / BK;

    // ---- prologue: stage tiles 0 and 1 ----
    #pragma unroll
    for (int i = 0; i < 4; ++i) STG_A(0, i, 0);
    #pragma unroll
    for (int i = 0; i < 4; ++i) STG_B(0, i, 0);
    if (nt > 1) {
        #pragma unroll
        for (int i = 0; i < 4; ++i) STG_A(1, i, BK);
        #pragma unroll
        for (int i = 0; i < 4; ++i) STG_B(1, i, BK);
    }

    f32x4 acc[8][4] = {};

    for (int tk = 0; tk < nt; ++tk) {
        const int bb = tk & 1;
        const uint16_t* lA = &lds[bb][0][0];
        const uint16_t* lB = &lds[bb][1][0];
        const int kk = (tk + 2) * BK;
        const bool pf = (tk + 2) < nt;

        if (tk + 1 < nt) { asm volatile("s_waitcnt vmcnt(8)" ::: "memory"); }
        else             { asm volatile("s_waitcnt vmcnt(0)" ::: "memory"); }
        __builtin_amdgcn_s_barrier();
        asm volatile("" ::: "memory");

        bf16x8 a[4][2], b0[2][2], b1[2][2];

        // ---- phase 0: read A-mh0 (8) + B-nh0 (4); MFMA quadrant (0,0) ----
        #pragma unroll
        for (int fi = 0; fi < 4; ++fi) {
            a[fi][0] = *(const bf16x8*)&lA[aBase + fi * 1024 + kx0];
            a[fi][1] = *(const bf16x8*)&lA[aBase + fi * 1024 + kx1];
        }
        #pragma unroll
        for (int fj = 0; fj < 2; ++fj) {
            b0[fj][0] = *(const bf16x8*)&lB[bBase + fj * 1024 + kx0];
            b0[fj][1] = *(const bf16x8*)&lB[bBase + fj * 1024 + kx1];
        }
        barfence();
        __builtin_amdgcn_s_setprio(1);
        MFMA16(a, b0, 0, 0);
        __builtin_amdgcn_s_setprio(0);
        barfence();

        // ---- phase 1: read B-nh1 (4); stage A-mh0 of tile tk+2; (0,1) ----
        #pragma unroll
        for (int fj = 0; fj < 2; ++fj) {
            b1[fj][0] = *(const bf16x8*)&lB[bBase + 2048 + fj * 1024 + kx0];
            b1[fj][1] = *(const bf16x8*)&lB[bBase + 2048 + fj * 1024 + kx1];
        }
        if (pf) { STG_A(bb, 0, kk); STG_A(bb, 2, kk); }
        barfence();
        __builtin_amdgcn_s_setprio(1);
        MFMA16(a, b1, 0, 1);
        __builtin_amdgcn_s_setprio(0);
        barfence();

        // ---- phase 2: read A-mh1 (8); stage B rows 0-127; (1,1) ----
        #pragma unroll
        for (int fi = 0; fi < 4; ++fi) {
            a[fi][0] = *(const bf16x8*)&lA[aBase + 4096 + fi * 1024 + kx0];
            a[fi][1] = *(const bf16x8*)&lA[aBase + 4096 + fi * 1024 + kx1];
        }
        if (pf) { STG_B(bb, 0, kk); STG_B(bb, 1, kk); }
        barfence();
        __builtin_amdgcn_s_setprio(1);
        MFMA16(a, b1, 1, 1);
        __builtin_amdgcn_s_setprio(0);
        barfence();

        // ---- phase 3: stage A-mh1 + B rows 128-255; (1,0) reuses b0 ----
        if (pf) { STG_A(bb, 1, kk); STG_A(bb, 3, kk);
                  STG_B(bb, 2, kk); STG_B(bb, 3, kk); }
        barfence();
        __builtin_amdgcn_s_setprio(1);
        MFMA16(a, b0, 1, 0);
        __builtin_amdgcn_s_setprio(0);
        // no trailing barrier: loop-top vmcnt+barrier separates iterations
    }

    // ---- epilogue: C/D layout col = lane&15, row = (lane>>4)*4 + reg ----
    #pragma unroll
    for (int fj = 0; fj < 4; ++fj) {
        const int col = nBase + (wn << 6) + fj * 16 + l15;
        const float bj = bias[col];
        #pragma unroll
        for (int fi = 0; fi < 8; ++fi) {
            const int row0 = mBase + (wm << 7) + fi * 16 + hi4;
            #pragma unroll
            for (int rr = 0; rr < 4; ++rr)
                C[(size_t)(row0 + rr) * N + col] = acc[fi][fj][rr] + bj;
        }
    }
}

extern "C" void kernel_launch(void* const* d_in, const int* in_sizes, int n_in,
                              void* d_out, int out_size, void* d_ws, size_t ws_size,
                              hipStream_t stream) {
    const float* x    = (const float*)d_in[0];
    const float* w    = (const float*)d_in[1];
    const float* bias = (const float*)d_in[2];
    float* out = (float*)d_out;

    const int N = in_sizes[2];            // bias length
    const int K = in_sizes[1] / N;        // weight is [N,K]
    const int M = in_sizes[0] / K;        // x is [M,K]

    uint16_t* xq = (uint16_t*)d_ws;                 // M*K bf16
    uint16_t* wq = xq + (size_t)M * K;              // N*K bf16 (contiguous)

    const int xgroups = (M * K) / 16;
    const int totgroups = xgroups + (N * K) / 16;
    quant_fp4_g16<<<(totgroups + 255) / 256, 256, 0, stream>>>(x, w, xq, xgroups, totgroups);

    const int nwg = (M >> 8) * (N >> 8);
    gemm_w4a4<<<nwg, THREADS, 0, stream>>>(xq, wq, bias, out, M, N, K);
}